// Round 2
// baseline (926.332 us; speedup 1.0000x reference)
//
#include <hip/hip_runtime.h>

// QuantizedConv2d: int8 3x3 conv, N=64, Cin=Cout=128, H=W=56, pad=1 (pad value =
// input_zero_point), int32 accum, per-channel requantize, output int8 values.
// Harness widens ALL integer arrays to int32 — inputs AND the output buffer
// (d_out is read back as np.int32; round-1 absmax 2^31 proved this: float
// -0.0f stores read as INT_MIN).
//
// Inputs (widened to int32 by harness for integer dtypes):
//  d_in[0] x      int32[64*128*56*56]   (int8 values)
//  d_in[1] weight int32[128*128*3*3]    (int8 values)
//  d_in[2] bias   int32[128]
//  d_in[3] input_scale  f32[1]
//  d_in[4] weight_scale f32[128]
//  d_in[5] output_scale f32[1]
//  d_in[6] input_zero_point  int32[1]
//  d_in[7] output_zero_point int32[1]

#define CIN  128
#define COUT 128
#define HW   56
#define NPIX (HW * HW)

// ---------------- kernel 1: pack weights int32 -> int8, layout [co][tap][ci] ----
// wp dword index i = (co*9 + t)*32 + ci4 ; dword holds ci4*4 .. ci4*4+3 (LE)
__global__ __launch_bounds__(256) void pack_w_kernel(const int* __restrict__ w_g,
                                                     unsigned* __restrict__ wp) {
    int i = blockIdx.x * 256 + threadIdx.x;
    if (i >= COUT * 9 * 32) return;
    int ci4 = i & 31;
    int t   = (i >> 5) % 9;
    int co  = i / (9 * 32);
    unsigned d = 0;
#pragma unroll
    for (int b = 0; b < 4; ++b) {
        int ci = ci4 * 4 + b;
        int v = w_g[(co * CIN + ci) * 9 + t];
        d |= (unsigned)(v & 0xFF) << (8 * b);
    }
    wp[i] = d;
}

// ---------------- kernel 2: conv ----------------
// One block per (n, ho). 256 threads = 4 waves.
// LDS x tile: rows ho-1..ho+1, whalo 0..63 (w = whalo-1), all 128 ci packed.
// Layout xs[ci4][r][wh] (dword idx = ci4*192 + r*64 + wh) -> compute-phase
// ds_read_b32 lanes stride-1 in wh => conflict-free.
// Compute: lane wo = tid&63 (wo>=56 lanes compute junk, skip store);
// wave cog = tid>>6 owns co block [cog*32, cog*32+32). acc[32] in VGPRs.
__global__ __launch_bounds__(256) void conv_kernel(
    const int* __restrict__ x_g, const unsigned* __restrict__ wp,
    const int* __restrict__ bias, const float* __restrict__ in_s,
    const float* __restrict__ w_s, const float* __restrict__ out_s,
    const int* __restrict__ zp_in_p, const int* __restrict__ zp_out_p,
    int* __restrict__ out) {
    __shared__ unsigned xs[32 * 3 * 64];  // 24.6 KB

    const int n  = blockIdx.x / HW;
    const int ho = blockIdx.x % HW;
    const int tid = threadIdx.x;

    const int zp = *zp_in_p;
    const unsigned zpd = (unsigned)(zp & 0xFF) * 0x01010101u;

    // ---- stage x rows (ho-1..ho+1) into LDS, int32 -> packed int8 ----
    // idx = ci4*192 + r*64 + wh ; lanes vary wh => coalesced global reads.
#pragma unroll
    for (int it = 0; it < 24; ++it) {
        int idx = it * 256 + tid;          // 0 .. 6143
        int wh  = idx & 63;
        int r   = (idx >> 6) % 3;
        int ci4 = idx / 192;
        int h = ho + r - 1;
        int w = wh - 1;
        unsigned d = zpd;
        if (h >= 0 && h < HW && w >= 0 && w < HW) {
            const int* xb = x_g + ((n * CIN + ci4 * 4) * HW + h) * HW + w;
            unsigned b0 = (unsigned)(xb[0] & 0xFF);
            unsigned b1 = (unsigned)(xb[NPIX] & 0xFF);
            unsigned b2 = (unsigned)(xb[2 * NPIX] & 0xFF);
            unsigned b3 = (unsigned)(xb[3 * NPIX] & 0xFF);
            d = b0 | (b1 << 8) | (b2 << 16) | (b3 << 24);
        }
        xs[idx] = d;  // idx == ci4*192 + r*64 + wh
    }
    __syncthreads();

    const int wo  = tid & 63;
    const int cog = tid >> 6;  // wave id 0..3 -> co base cog*32

    int acc[32];
#pragma unroll
    for (int c = 0; c < 32; ++c) acc[c] = 0;

    for (int t = 0; t < 9; ++t) {
        const int r  = t / 3;
        const int kw = t - 3 * r;
        int wh = wo + kw;
        if (wh > 63) wh = 63;              // junk lanes only; keep in-bounds
        const unsigned* xcol = &xs[r * 64 + wh];              // + ci4*192
        const unsigned* wrow = wp + (cog * 32 * 9 + t) * 32;  // + c*288 + ci4

        for (int g = 0; g < 8; ++g) {      // ci4 groups of 4
            const int ci4 = g * 4;
            unsigned x0 = xcol[(ci4 + 0) * 192];
            unsigned x1 = xcol[(ci4 + 1) * 192];
            unsigned x2 = xcol[(ci4 + 2) * 192];
            unsigned x3 = xcol[(ci4 + 3) * 192];
#pragma unroll
            for (int c = 0; c < 32; ++c) {
                const unsigned* wr = wrow + c * 288 + ci4;
                int a = acc[c];
                a = __builtin_amdgcn_sdot4((int)x0, (int)wr[0], a, false);
                a = __builtin_amdgcn_sdot4((int)x1, (int)wr[1], a, false);
                a = __builtin_amdgcn_sdot4((int)x2, (int)wr[2], a, false);
                a = __builtin_amdgcn_sdot4((int)x3, (int)wr[3], a, false);
                acc[c] = a;
            }
        }
    }

    // ---- requantize epilogue (store as int32 — harness reads np.int32) ----
    const float s_ratio = (*in_s) / (*out_s);
    const float zpo = (float)(*zp_out_p);
    if (wo < HW) {
        int* ob = out + ((n * COUT + cog * 32) * HW + ho) * HW + wo;
#pragma unroll
        for (int c = 0; c < 32; ++c) {
            const int co = cog * 32 + c;
            float f = (float)(acc[c] + bias[co]) * (s_ratio * w_s[co]) + zpo;
            f = rintf(f);
            f = fminf(fmaxf(f, -128.0f), 127.0f);
            ob[c * NPIX] = (int)f;
        }
    }
}

extern "C" void kernel_launch(void* const* d_in, const int* in_sizes, int n_in,
                              void* d_out, int out_size, void* d_ws, size_t ws_size,
                              hipStream_t stream) {
    const int* x_g      = (const int*)d_in[0];
    const int* w_g      = (const int*)d_in[1];
    const int* bias     = (const int*)d_in[2];
    const float* in_s   = (const float*)d_in[3];
    const float* w_s    = (const float*)d_in[4];
    const float* out_s  = (const float*)d_in[5];
    const int* zp_in_p  = (const int*)d_in[6];
    const int* zp_out_p = (const int*)d_in[7];
    int* outp = (int*)d_out;
    unsigned* wp = (unsigned*)d_ws;  // 147456 bytes used

    const int wp_dwords = COUT * 9 * 32;
    pack_w_kernel<<<(wp_dwords + 255) / 256, 256, 0, stream>>>(w_g, wp);

    const int nblocks = 64 * HW;  // (n, ho)
    conv_kernel<<<nblocks, 256, 0, stream>>>(x_g, wp, bias, in_s, w_s, out_s,
                                             zp_in_p, zp_out_p, outp);
}

// Round 3
// 109.547 us; speedup vs baseline: 8.4560x; 8.4560x over previous
//
#include <hip/hip_runtime.h>

// QuantizedConv2d int8 3x3, N=64, Cin=Cout=128, 56x56, pad=1 (value = input zp),
// int32 accum, per-channel requant. Harness widens integer arrays to int32
// (inputs AND output).
//
// R3: implicit GEMM via v_mfma_i32_32x32x32_i8.
//  GEMM: M=pixels(200704), N=cout(128), K=ci*taps(1152).
//  Block = (n, 4 output rows) = 224 px, all 128 cout. 256 thr = 4 waves.
//  Wave: 2 M-tiles(32px) x 4 N-tiles(32co); acc = 8 x 16 i32.
//  x staged once to LDS as [q=pixel][ci] bytes, dword-XOR swizzle (q&7)<<2.
//  B (weights) pre-packed to [step][cout][32B ci-slot], read from L2 per step.

#define CIN  128
#define COUT 128
#define HW   56
#define NPIX (HW * HW)
#define ROWS  4
#define QROWS 6
#define QCOLS 58
#define NQ (QROWS * QCOLS)   // 348

typedef int v4i  __attribute__((ext_vector_type(4)));
typedef int v16i __attribute__((ext_vector_type(16)));

// ---- pack weights: wp2 dword i = ((step)*128 + cout)*8 + dw ; step = t*4+cb ;
// byte b of dword dw -> ci = cb*32 + dw*4 + b, tap t.
__global__ __launch_bounds__(256) void pack_w2(const int* __restrict__ w_g,
                                               unsigned* __restrict__ wp2) {
    int i = blockIdx.x * 256 + threadIdx.x;
    if (i >= 36 * 128 * 8) return;
    int dw   = i & 7;
    int cout = (i >> 3) & 127;
    int step = i >> 10;          // 0..35
    int t  = step >> 2;
    int cb = step & 3;
    unsigned d = 0;
#pragma unroll
    for (int b = 0; b < 4; ++b) {
        int ci = cb * 32 + dw * 4 + b;
        int v = w_g[(cout * CIN + ci) * 9 + t];
        d |= (unsigned)(v & 0xFF) << (8 * b);
    }
    wp2[i] = d;
}

__global__ __launch_bounds__(256, 2) void conv_mfma(
    const int* __restrict__ x_g, const unsigned char* __restrict__ wp2,
    const int* __restrict__ bias, const float* __restrict__ in_s,
    const float* __restrict__ w_s, const float* __restrict__ out_s,
    const int* __restrict__ zp_in_p, const int* __restrict__ zp_out_p,
    int* __restrict__ out) {
    __shared__ unsigned xs[NQ * 32];   // [q][ci/4] dwords, 44544 B

    const int n   = blockIdx.x / 14;
    const int ho0 = (blockIdx.x % 14) * ROWS;
    const int tid  = threadIdx.x;
    const int lane = tid & 63;
    const int wave = tid >> 6;

    const unsigned zpd = (unsigned)((*zp_in_p) & 0xFF) * 0x01010101u;

    // ---- stage x tile: rows ho0-1..ho0+4, cols -1..56, all 128 ci ----
    // lane-dim = col (coalesced global); LDS dword = q*32 + (ci4 ^ ((q&7)<<2))
#pragma unroll
    for (int it = 0; it < 48; ++it) {
        int idx = it * 256 + tid;        // 0..12287
        int col = idx & 63;              // 0..63 (>=58 dead)
        int ci4 = (idx >> 6) & 31;
        int hr  = idx >> 11;             // 0..5
        if (col < QCOLS) {
            int h = ho0 + hr - 1;
            int w = col - 1;
            unsigned d = zpd;
            if (h >= 0 && h < HW && w >= 0 && w < HW) {
                const int* xb = x_g + ((n * CIN + ci4 * 4) * HW + h) * HW + w;
                d = (unsigned)(xb[0] & 0xFF) | ((unsigned)(xb[NPIX] & 0xFF) << 8) |
                    ((unsigned)(xb[2 * NPIX] & 0xFF) << 16) |
                    ((unsigned)(xb[3 * NPIX] & 0xFF) << 24);
            }
            int q = hr * QCOLS + col;
            xs[q * 32 + (ci4 ^ ((q & 7) << 2))] = d;
        }
    }
    __syncthreads();

    // ---- per-lane M geometry: mt = wave*2 + i, px = mt*32 + (lane&31) ----
    int qb[2];
#pragma unroll
    for (int i = 0; i < 2; ++i) {
        int px = (wave * 2 + i) * 32 + (lane & 31);
        if (px > 223) px = 223;          // pad tile (wave 3, i=1): clamp
        qb[i] = (px / HW) * QCOLS + (px % HW);
    }
    const int h4 = (lane >> 5) * 4;      // dword offset of 16B half

    v16i acc[2][4];
#pragma unroll
    for (int i = 0; i < 2; ++i)
#pragma unroll
        for (int j = 0; j < 4; ++j) acc[i][j] = (v16i)0;

    const unsigned char* bbase = wp2 + (lane & 31) * 32 + h4 * 4;

    // ---- K loop: 9 taps x 4 ci-blocks ----
#pragma unroll 1
    for (int t = 0; t < 9; ++t) {
        const int dq = (t / 3) * QCOLS + (t % 3);
        const int q0 = qb[0] + dq, q1 = qb[1] + dq;
        const int s0 = (q0 & 7) << 2, s1 = (q1 & 7) << 2;
        const unsigned char* bt = bbase + t * 4 * 4096;
#pragma unroll
        for (int cb = 0; cb < 4; ++cb) {
            v4i a0 = *(const v4i*)&xs[q0 * 32 + ((cb * 8 + h4) ^ s0)];
            v4i a1 = *(const v4i*)&xs[q1 * 32 + ((cb * 8 + h4) ^ s1)];
            const unsigned char* bp = bt + cb * 4096;
            v4i b0 = *(const v4i*)(bp);
            v4i b1 = *(const v4i*)(bp + 1024);
            v4i b2 = *(const v4i*)(bp + 2048);
            v4i b3 = *(const v4i*)(bp + 3072);
            acc[0][0] = __builtin_amdgcn_mfma_i32_32x32x32_i8(a0, b0, acc[0][0], 0, 0, 0);
            acc[0][1] = __builtin_amdgcn_mfma_i32_32x32x32_i8(a0, b1, acc[0][1], 0, 0, 0);
            acc[0][2] = __builtin_amdgcn_mfma_i32_32x32x32_i8(a0, b2, acc[0][2], 0, 0, 0);
            acc[0][3] = __builtin_amdgcn_mfma_i32_32x32x32_i8(a0, b3, acc[0][3], 0, 0, 0);
            acc[1][0] = __builtin_amdgcn_mfma_i32_32x32x32_i8(a1, b0, acc[1][0], 0, 0, 0);
            acc[1][1] = __builtin_amdgcn_mfma_i32_32x32x32_i8(a1, b1, acc[1][1], 0, 0, 0);
            acc[1][2] = __builtin_amdgcn_mfma_i32_32x32x32_i8(a1, b2, acc[1][2], 0, 0, 0);
            acc[1][3] = __builtin_amdgcn_mfma_i32_32x32x32_i8(a1, b3, acc[1][3], 0, 0, 0);
        }
    }

    // ---- requant epilogue: D col = lane&31 (cout), row = (reg&3)+8*(reg>>2)+4*(lane>>5) ----
    const float s_ratio = (*in_s) / (*out_s);
    const float zpo = (float)(*zp_out_p);
    const int rbase = 4 * (lane >> 5);
#pragma unroll
    for (int nt = 0; nt < 4; ++nt) {
        const int co = nt * 32 + (lane & 31);
        const float sc = s_ratio * w_s[co];
        const int bi = bias[co];
        int* ob = out + (n * COUT + co) * NPIX;
#pragma unroll
        for (int i = 0; i < 2; ++i) {
            const int mt = wave * 2 + i;
#pragma unroll
            for (int reg = 0; reg < 16; ++reg) {
                int px = mt * 32 + (reg & 3) + 8 * (reg >> 2) + rbase;
                if (px < ROWS * HW) {
                    int row = px / HW, wo = px - row * HW;
                    float f = (float)(acc[i][nt][reg] + bi) * sc + zpo;
                    f = rintf(f);
                    f = fminf(fmaxf(f, -128.0f), 127.0f);
                    ob[(ho0 + row) * HW + wo] = (int)f;
                }
            }
        }
    }
}

extern "C" void kernel_launch(void* const* d_in, const int* in_sizes, int n_in,
                              void* d_out, int out_size, void* d_ws, size_t ws_size,
                              hipStream_t stream) {
    const int* x_g      = (const int*)d_in[0];
    const int* w_g      = (const int*)d_in[1];
    const int* bias     = (const int*)d_in[2];
    const float* in_s   = (const float*)d_in[3];
    const float* w_s    = (const float*)d_in[4];
    const float* out_s  = (const float*)d_in[5];
    const int* zp_in_p  = (const int*)d_in[6];
    const int* zp_out_p = (const int*)d_in[7];
    int* outp = (int*)d_out;
    unsigned* wp2 = (unsigned*)d_ws;   // 147456 B

    pack_w2<<<(36 * 128 * 8 + 255) / 256, 256, 0, stream>>>(w_g, wp2);

    const int nblocks = 64 * (HW / ROWS);   // 896
    conv_mfma<<<nblocks, 256, 0, stream>>>(x_g, (const unsigned char*)wp2, bias,
                                           in_s, w_s, out_s, zp_in_p, zp_out_p, outp);
}